// Round 12
// baseline (750.158 us; speedup 1.0000x reference)
//
#include <hip/hip_runtime.h>

#define HWD 884736   // 96*96*96
#define KCLS 5
#define CCH 64
#define NC 4

constexpr int PLANE4 = HWD / 4;          // float4 groups per channel plane (221184)
constexpr int GRP_B  = HWD / 4;          // voxel-groups per batch item
constexpr int NBLK   = 2 * GRP_B / 256;  // 1728 blocks of 256 groups
constexpr int NPART  = 16;
constexpr int PARTSZ = 272;              // 256 sums + 4 cnt @256 + 4 sq @260

__global__ __launch_bounds__(256) void pm_zero(float* __restrict__ part) {
    const int n = NPART * PARTSZ;
    for (int i = threadIdx.x; i < n; i += 256) part[i] = 0.f;
}

// acc is float4[16]; flat index f in [0,64): channel-in-wave f>>2, class f&3.
// All indices compile-time after unrolling (rule #20: no runtime indexing).
#define ACCF(i) (((float*)&acc[(i) >> 2])[(i) & 3])

// One butterfly reduce-scatter stage with LITERAL count/mask.
#define RSTAGE(M, CNT)                                                  \
    {                                                                   \
        _Pragma("unroll")                                               \
        for (int i = 0; i < CNT; ++i) {                                 \
            const float send = hi##M ? ACCF(i) : ACCF(i + M);           \
            const float recv = __shfl_xor(send, M);                     \
            ACCF(i) = (hi##M ? ACCF(i + M) : ACCF(i)) + recv;           \
        }                                                               \
    }

// Fused: mask (pred/label -> 3b/voxel in LDS) + predicated dense feat sweep
// (exec-masked loads keep the sequential page walk; ~58% of lines skipped),
// register-resident accumulation + in-register butterfly reduce-scatter.
__global__ __launch_bounds__(256, 3) void pm_main(
    const float* __restrict__ feat, const float* __restrict__ pred,
    const int* __restrict__ label, const unsigned char* __restrict__ is_lab,
    float* __restrict__ part)
{
    __shared__ unsigned int smask[256];
    __shared__ float lcnt[NC];

    const int t = threadIdx.x, w = t >> 6, l = t & 63;
    const int bi = blockIdx.x;
    const int b = (bi >= NBLK / 2);                  // block never straddles batch
    const int g0 = bi * 256 - b * GRP_B;             // group base within batch plane

    if (t < NC) lcnt[t] = 0.f;
    __syncthreads();

    // ---- phase A: mask from pred/label (coalesced), one group per thread ----
    {
        const int gg = g0 + t;
        const float4* pb = (const float4*)(pred + (size_t)b * KCLS * HWD) + gg;
        float4 pk[KCLS];
        #pragma unroll
        for (int k = 0; k < KCLS; ++k) pk[k] = pb[(size_t)k * PLANE4];
        const int4 lb = ((const int4*)(label + (size_t)b * HWD))[gg];
        const bool lab = is_lab[b] != 0;

        unsigned int wd = 0;
        #pragma unroll
        for (int j = 0; j < 4; ++j) {
            float best = -1.f; int c = 0;
            #pragma unroll
            for (int k = 0; k < KCLS; ++k) {
                float v = ((const float*)&pk[k])[j];
                if (v > best) { best = v; c = k; }   // first-max == jnp.argmax
            }
            const int lj = ((const int*)&lb)[j];
            const bool m = (best > 0.8f) & (c > 0) & ((c == lj) | (!lab));
            if (m) {
                wd |= (4u | (unsigned)(c - 1)) << (3 * j);
                atomicAdd(&lcnt[c - 1], 1.f);
            }
        }
        smask[t] = wd;
    }
    __syncthreads();

    // ---- phase B: predicated dense sweep; wave w owns channels [16w,16w+16) ----
    const float4* fb = (const float4*)feat + (size_t)b * CCH * PLANE4;
    const int c0 = w * 16;

    float4 acc[16];
    #pragma unroll
    for (int u = 0; u < 16; ++u) acc[u] = make_float4(0.f, 0.f, 0.f, 0.f);
    float sq[NC] = {0.f, 0.f, 0.f, 0.f};

    for (int i = 0; i < 4; ++i) {
        const int gl = i * 64 + l;                   // group within block
        const int gg = g0 + gl;
        const unsigned int wm = smask[gl];
        const bool act = (wm != 0);                  // lane has any masked voxel

        float ind[4][NC];
        #pragma unroll
        for (int j = 0; j < 4; ++j) {
            const int bits = (wm >> (3 * j)) & 7;
            #pragma unroll
            for (int k = 0; k < NC; ++k)
                ind[j][k] = (bits == (4 | k)) ? 1.f : 0.f;
        }

        float vsq[4] = {0.f, 0.f, 0.f, 0.f};
        #pragma unroll
        for (int half = 0; half < 2; ++half) {
            float4 fv[8];
            #pragma unroll
            for (int u = 0; u < 8; ++u) fv[u] = make_float4(0.f, 0.f, 0.f, 0.f);
            if (act) {
                #pragma unroll
                for (int u = 0; u < 8; ++u)
                    fv[u] = fb[(size_t)(c0 + half * 8 + u) * PLANE4 + gg];  // exec-masked
            }
            #pragma unroll
            for (int u = 0; u < 8; ++u) {
                const int uc = half * 8 + u;
                #pragma unroll
                for (int j = 0; j < 4; ++j) {
                    const float v = ((const float*)&fv[u])[j];
                    vsq[j] = fmaf(v, v, vsq[j]);
                    #pragma unroll
                    for (int k = 0; k < NC; ++k)
                        ((float*)&acc[uc])[k] = fmaf(ind[j][k], v, ((float*)&acc[uc])[k]);
                }
            }
        }
        #pragma unroll
        for (int j = 0; j < 4; ++j)
            #pragma unroll
            for (int k = 0; k < NC; ++k)
                sq[k] = fmaf(ind[j][k], vsq[j], sq[k]);
    }

    // ---- 6-stage butterfly reduce-scatter: lane L ends with the block-wave
    //      total for flat index L (channel c0 + (L>>2), class L&3) ----
    {
        const bool hi32 = (l & 32) != 0;  RSTAGE(32, 32)
        const bool hi16 = (l & 16) != 0;  RSTAGE(16, 16)
        const bool hi8  = (l & 8)  != 0;  RSTAGE(8, 8)
        const bool hi4  = (l & 4)  != 0;  RSTAGE(4, 4)
        const bool hi2  = (l & 2)  != 0;  RSTAGE(2, 2)
        const bool hi1  = (l & 1)  != 0;  RSTAGE(1, 1)
    }

    float* dst = part + (size_t)(bi & (NPART - 1)) * PARTSZ;
    {
        const float tot = ACCF(0);
        const int cc = c0 + (l >> 2), kk = l & 3;
        if (tot != 0.f) atomicAdd(&dst[kk * 64 + cc], tot);
    }

    // per-wave sumsq butterfly + flush
    #pragma unroll
    for (int k = 0; k < NC; ++k) {
        float v = sq[k];
        #pragma unroll
        for (int o = 1; o < 64; o <<= 1) v += __shfl_xor(v, o);
        sq[k] = v;
    }
    if (l < NC) {
        float v = (l == 0) ? sq[0] : (l == 1) ? sq[1] : (l == 2) ? sq[2] : sq[3];
        if (v != 0.f) atomicAdd(&dst[260 + l], v);
    }
    if (t < NC) { float c = lcnt[t]; if (c != 0.f) atomicAdd(&dst[256 + t], c); }
}

__global__ __launch_bounds__(256) void pm_pass2(
    const float* __restrict__ part, const float* __restrict__ proto,
    float* __restrict__ out)
{
    __shared__ float scnt[NC], ssq[NC], smu[NC * CCH], sred[4];
    __shared__ float s_intra;
    const int t = threadIdx.x;
    const int q = t >> 6;

    float s = 0.f;
    #pragma unroll
    for (int p = 0; p < NPART; ++p) s += part[p * PARTSZ + t];
    if (t < 2 * NC) {
        float a = 0.f;
        #pragma unroll
        for (int p = 0; p < NPART; ++p) a += part[p * PARTSZ + 256 + t];
        if (t < NC) scnt[t] = a; else ssq[t - NC] = a;
    }
    __syncthreads();

    const float cq = scnt[q];
    const float mean = s / fmaxf(cq, 1.f);
    const float pold = proto[t];                       // (4,64) row-major == t
    const float mu = (cq > 0.f) ? 0.9f * pold + 0.1f * mean : pold;
    out[3 + t] = mu;
    smu[t] = mu;

    // loss_intra numerator partial: -2*sums*mu + cnt*mu^2  (sumsq added at the end)
    float pi = -2.f * s * mu + cq * mu * mu;
    #pragma unroll
    for (int o = 1; o < 64; o <<= 1) pi += __shfl_xor(pi, o);
    if ((t & 63) == 0) sred[t >> 6] = pi;
    __syncthreads();

    if (t == 0) {
        float num = sred[0] + sred[1] + sred[2] + sred[3]
                  + ssq[0] + ssq[1] + ssq[2] + ssq[3];
        float nv = scnt[0] + scnt[1] + scnt[2] + scnt[3];
        s_intra = num / fmaxf(nv, 1.f);
    }
    __syncthreads();

    if (t < 64) {
        const int pi_[6] = {0, 0, 0, 1, 1, 2};
        const int pj_[6] = {1, 2, 3, 2, 3, 3};
        float acc = 0.f;
        #pragma unroll
        for (int e = 0; e < 6; ++e) {
            float d = smu[pi_[e] * 64 + t] - smu[pj_[e] * 64 + t];
            float d2 = d * d;
            #pragma unroll
            for (int o = 1; o < 64; o <<= 1) d2 += __shfl_xor(d2, o);
            float dist = sqrtf(d2 + 1e-12f);
            float vv = fmaxf(1.f - dist, 0.f);
            acc += vv * vv;
        }
        if (t == 0) {
            float li = acc / 6.f;                      // n_pairs = 6
            out[0] = s_intra + 0.1f * li;              // lambda_intra=1, lambda_inter=0.1
            out[1] = s_intra;
            out[2] = li;
        }
    }
}

extern "C" void kernel_launch(void* const* d_in, const int* in_sizes, int n_in,
                              void* d_out, int out_size, void* d_ws, size_t ws_size,
                              hipStream_t stream) {
    const float* feat         = (const float*)d_in[0];
    const float* pred         = (const float*)d_in[1];
    const int* label          = (const int*)d_in[2];
    const unsigned char* ilab = (const unsigned char*)d_in[3];   // jnp bool = 1 byte
    const float* proto        = (const float*)d_in[4];
    float* out                = (float*)d_out;
    float* part               = (float*)d_ws;

    hipLaunchKernelGGL(pm_zero, dim3(1),    dim3(256), 0, stream, part);
    hipLaunchKernelGGL(pm_main, dim3(NBLK), dim3(256), 0, stream,
                       feat, pred, label, ilab, part);
    hipLaunchKernelGGL(pm_pass2, dim3(1),   dim3(256), 0, stream, part, proto, out);
}

// Round 13
// 107.650 us; speedup vs baseline: 6.9685x; 6.9685x over previous
//
#include <hip/hip_runtime.h>

#define HWD 884736   // 96*96*96
#define KCLS 5
#define CCH 64
#define NC 4

constexpr int PLANE4 = HWD / 4;          // float4 groups per channel plane (221184)
constexpr int GRP_B  = HWD / 4;          // voxel-groups per batch item
constexpr int NBLK   = 2 * GRP_B / 256;  // 1728 blocks of 256 groups
constexpr int NPART  = 16;
constexpr int PARTSZ = 272;              // 256 sums + 4 cnt @256 + 4 sq @260

__global__ __launch_bounds__(256) void pm_zero(float* __restrict__ part) {
    const int n = NPART * PARTSZ;
    for (int i = threadIdx.x; i < n; i += 256) part[i] = 0.f;
}

// acc is float4[16]; flat index f in [0,64): channel-in-wave f>>2, class f&3.
// All indices compile-time after unrolling (rule #20: no runtime indexing).
#define ACCF(i) (((float*)&acc[(i) >> 2])[(i) & 3])

// One butterfly reduce-scatter stage with LITERAL count/mask.
#define RSTAGE(M, CNT)                                                  \
    {                                                                   \
        _Pragma("unroll")                                               \
        for (int i = 0; i < CNT; ++i) {                                 \
            const float send = hi##M ? ACCF(i) : ACCF(i + M);           \
            const float recv = __shfl_xor(send, M);                     \
            ACCF(i) = (hi##M ? ACCF(i + M) : ACCF(i)) + recv;           \
        }                                                               \
    }

// Fused: mask (pred/label -> 3b/voxel in LDS) + line-sparse dense-order sweep.
// Predication is on the ADDRESS (v_cndmask), never on data: inactive lanes
// load a block-uniform dummy group (1 extra line/instr, coalesced broadcast);
// their garbage values are annihilated by ind==0. No branch -> no spill.
__global__ __launch_bounds__(256, 2) void pm_main(
    const float* __restrict__ feat, const float* __restrict__ pred,
    const int* __restrict__ label, const unsigned char* __restrict__ is_lab,
    float* __restrict__ part)
{
    __shared__ unsigned int smask[256];
    __shared__ float lcnt[NC];

    const int t = threadIdx.x, w = t >> 6, l = t & 63;
    const int bi = blockIdx.x;
    const int b = (bi >= NBLK / 2);                  // block never straddles batch
    const int g0 = bi * 256 - b * GRP_B;             // group base within batch plane

    if (t < NC) lcnt[t] = 0.f;
    __syncthreads();

    // ---- phase A: mask from pred/label (coalesced), one group per thread ----
    {
        const int gg = g0 + t;
        const float4* pb = (const float4*)(pred + (size_t)b * KCLS * HWD) + gg;
        float4 pk[KCLS];
        #pragma unroll
        for (int k = 0; k < KCLS; ++k) pk[k] = pb[(size_t)k * PLANE4];
        const int4 lb = ((const int4*)(label + (size_t)b * HWD))[gg];
        const bool lab = is_lab[b] != 0;

        unsigned int wd = 0;
        #pragma unroll
        for (int j = 0; j < 4; ++j) {
            float best = -1.f; int c = 0;
            #pragma unroll
            for (int k = 0; k < KCLS; ++k) {
                float v = ((const float*)&pk[k])[j];
                if (v > best) { best = v; c = k; }   // first-max == jnp.argmax
            }
            const int lj = ((const int*)&lb)[j];
            const bool m = (best > 0.8f) & (c > 0) & ((c == lj) | (!lab));
            if (m) {
                wd |= (4u | (unsigned)(c - 1)) << (3 * j);
                atomicAdd(&lcnt[c - 1], 1.f);
            }
        }
        smask[t] = wd;
    }
    __syncthreads();

    // ---- phase B: line-sparse sweep; wave w owns channels [16w, 16w+16) ----
    const float4* fb = (const float4*)feat + (size_t)b * CCH * PLANE4;
    const int c0 = w * 16;

    float4 acc[16];
    #pragma unroll
    for (int u = 0; u < 16; ++u) acc[u] = make_float4(0.f, 0.f, 0.f, 0.f);
    float sq[NC] = {0.f, 0.f, 0.f, 0.f};

    for (int i = 0; i < 4; ++i) {
        const int gl = i * 64 + l;                   // group within block
        const unsigned int wm = smask[gl];
        // address select: inactive lanes read block-uniform dummy group g0
        const int gg = wm ? (g0 + gl) : g0;

        float ind[4][NC];
        #pragma unroll
        for (int j = 0; j < 4; ++j) {
            const int bits = (wm >> (3 * j)) & 7;
            #pragma unroll
            for (int k = 0; k < NC; ++k)
                ind[j][k] = (bits == (4 | k)) ? 1.f : 0.f;
        }

        float vsq[4] = {0.f, 0.f, 0.f, 0.f};
        #pragma unroll
        for (int half = 0; half < 2; ++half) {
            float4 fv[8];
            #pragma unroll
            for (int u = 0; u < 8; ++u)
                fv[u] = fb[(size_t)(c0 + half * 8 + u) * PLANE4 + gg];  // unconditional
            #pragma unroll
            for (int u = 0; u < 8; ++u) {
                const int uc = half * 8 + u;
                #pragma unroll
                for (int j = 0; j < 4; ++j) {
                    const float v = ((const float*)&fv[u])[j];
                    vsq[j] = fmaf(v, v, vsq[j]);
                    #pragma unroll
                    for (int k = 0; k < NC; ++k)
                        ((float*)&acc[uc])[k] = fmaf(ind[j][k], v, ((float*)&acc[uc])[k]);
                }
            }
        }
        #pragma unroll
        for (int j = 0; j < 4; ++j)
            #pragma unroll
            for (int k = 0; k < NC; ++k)
                sq[k] = fmaf(ind[j][k], vsq[j], sq[k]);
    }

    // ---- 6-stage butterfly reduce-scatter: lane L ends with the block-wave
    //      total for flat index L (channel c0 + (L>>2), class L&3) ----
    {
        const bool hi32 = (l & 32) != 0;  RSTAGE(32, 32)
        const bool hi16 = (l & 16) != 0;  RSTAGE(16, 16)
        const bool hi8  = (l & 8)  != 0;  RSTAGE(8, 8)
        const bool hi4  = (l & 4)  != 0;  RSTAGE(4, 4)
        const bool hi2  = (l & 2)  != 0;  RSTAGE(2, 2)
        const bool hi1  = (l & 1)  != 0;  RSTAGE(1, 1)
    }

    float* dst = part + (size_t)(bi & (NPART - 1)) * PARTSZ;
    {
        const float tot = ACCF(0);
        const int cc = c0 + (l >> 2), kk = l & 3;
        if (tot != 0.f) atomicAdd(&dst[kk * 64 + cc], tot);
    }

    // per-wave sumsq butterfly + flush
    #pragma unroll
    for (int k = 0; k < NC; ++k) {
        float v = sq[k];
        #pragma unroll
        for (int o = 1; o < 64; o <<= 1) v += __shfl_xor(v, o);
        sq[k] = v;
    }
    if (l < NC) {
        float v = (l == 0) ? sq[0] : (l == 1) ? sq[1] : (l == 2) ? sq[2] : sq[3];
        if (v != 0.f) atomicAdd(&dst[260 + l], v);
    }
    if (t < NC) { float c = lcnt[t]; if (c != 0.f) atomicAdd(&dst[256 + t], c); }
}

__global__ __launch_bounds__(256) void pm_pass2(
    const float* __restrict__ part, const float* __restrict__ proto,
    float* __restrict__ out)
{
    __shared__ float scnt[NC], ssq[NC], smu[NC * CCH], sred[4];
    __shared__ float s_intra;
    const int t = threadIdx.x;
    const int q = t >> 6;

    float s = 0.f;
    #pragma unroll
    for (int p = 0; p < NPART; ++p) s += part[p * PARTSZ + t];
    if (t < 2 * NC) {
        float a = 0.f;
        #pragma unroll
        for (int p = 0; p < NPART; ++p) a += part[p * PARTSZ + 256 + t];
        if (t < NC) scnt[t] = a; else ssq[t - NC] = a;
    }
    __syncthreads();

    const float cq = scnt[q];
    const float mean = s / fmaxf(cq, 1.f);
    const float pold = proto[t];                       // (4,64) row-major == t
    const float mu = (cq > 0.f) ? 0.9f * pold + 0.1f * mean : pold;
    out[3 + t] = mu;
    smu[t] = mu;

    // loss_intra numerator partial: -2*sums*mu + cnt*mu^2  (sumsq added at the end)
    float pi = -2.f * s * mu + cq * mu * mu;
    #pragma unroll
    for (int o = 1; o < 64; o <<= 1) pi += __shfl_xor(pi, o);
    if ((t & 63) == 0) sred[t >> 6] = pi;
    __syncthreads();

    if (t == 0) {
        float num = sred[0] + sred[1] + sred[2] + sred[3]
                  + ssq[0] + ssq[1] + ssq[2] + ssq[3];
        float nv = scnt[0] + scnt[1] + scnt[2] + scnt[3];
        s_intra = num / fmaxf(nv, 1.f);
    }
    __syncthreads();

    if (t < 64) {
        const int pi_[6] = {0, 0, 0, 1, 1, 2};
        const int pj_[6] = {1, 2, 3, 2, 3, 3};
        float acc = 0.f;
        #pragma unroll
        for (int e = 0; e < 6; ++e) {
            float d = smu[pi_[e] * 64 + t] - smu[pj_[e] * 64 + t];
            float d2 = d * d;
            #pragma unroll
            for (int o = 1; o < 64; o <<= 1) d2 += __shfl_xor(d2, o);
            float dist = sqrtf(d2 + 1e-12f);
            float vv = fmaxf(1.f - dist, 0.f);
            acc += vv * vv;
        }
        if (t == 0) {
            float li = acc / 6.f;                      // n_pairs = 6
            out[0] = s_intra + 0.1f * li;              // lambda_intra=1, lambda_inter=0.1
            out[1] = s_intra;
            out[2] = li;
        }
    }
}

extern "C" void kernel_launch(void* const* d_in, const int* in_sizes, int n_in,
                              void* d_out, int out_size, void* d_ws, size_t ws_size,
                              hipStream_t stream) {
    const float* feat         = (const float*)d_in[0];
    const float* pred         = (const float*)d_in[1];
    const int* label          = (const int*)d_in[2];
    const unsigned char* ilab = (const unsigned char*)d_in[3];   // jnp bool = 1 byte
    const float* proto        = (const float*)d_in[4];
    float* out                = (float*)d_out;
    float* part               = (float*)d_ws;

    hipLaunchKernelGGL(pm_zero, dim3(1),    dim3(256), 0, stream, part);
    hipLaunchKernelGGL(pm_main, dim3(NBLK), dim3(256), 0, stream,
                       feat, pred, label, ilab, part);
    hipLaunchKernelGGL(pm_pass2, dim3(1),   dim3(256), 0, stream, part, proto, out);
}

// Round 14
// 105.819 us; speedup vs baseline: 7.0890x; 1.0173x over previous
//
#include <hip/hip_runtime.h>

#define HWD 884736   // 96*96*96
#define KCLS 5
#define CCH 64
#define NC 4

constexpr int PLANE4 = HWD / 4;          // float4 groups per channel plane (221184)
constexpr int GRP_B  = HWD / 4;          // voxel-groups per batch item
constexpr int NBLKM  = 2 * GRP_B / 256;  // 1728 mask blocks of 256 groups
constexpr int NPART  = 16;
constexpr int PARTSZ = 272;              // 256 sums + 4 cnt @256 + 4 sq @260
constexpr int MASK_OFF_BYTES = 32768;

constexpr int ITER = 27;                 // groups per thread in sweep
constexpr int SEGG = 256 * ITER;         // 6912 groups per block (110.6 KB)
constexpr int NSEG = PLANE4 / SEGG;      // 32 segments per channel plane (exact)
constexpr int NBLKS = 2 * CCH * NSEG;    // 4096 sweep blocks

__global__ __launch_bounds__(256) void pm_zero(float* __restrict__ part) {
    const int n = NPART * PARTSZ;
    for (int i = threadIdx.x; i < n; i += 256) part[i] = 0.f;
}

// K1: per-voxel mask word (4 voxels x 3 bits: valid|class2) + class counts
__global__ __launch_bounds__(256) void pm_mask(
    const float* __restrict__ pred, const int* __restrict__ label,
    const unsigned char* __restrict__ is_lab,
    unsigned int* __restrict__ mask, float* __restrict__ part)
{
    __shared__ float lcnt[NC];
    const int t = threadIdx.x;
    if (t < NC) lcnt[t] = 0.f;
    __syncthreads();

    const int g = blockIdx.x * 256 + t;          // global float4-group id
    const int b = (blockIdx.x >= NBLKM / 2);     // block never straddles batch
    const int gg = g - b * GRP_B;

    const float4* pb = (const float4*)(pred + (size_t)b * KCLS * HWD) + gg;
    float4 pk[KCLS];
    #pragma unroll
    for (int k = 0; k < KCLS; ++k) pk[k] = pb[(size_t)k * PLANE4];
    const int4 lb = ((const int4*)(label + (size_t)b * HWD))[gg];
    const bool lab = is_lab[b] != 0;

    unsigned int wd = 0;
    #pragma unroll
    for (int j = 0; j < 4; ++j) {
        float best = -1.f; int c = 0;
        #pragma unroll
        for (int k = 0; k < KCLS; ++k) {
            float v = ((const float*)&pk[k])[j];
            if (v > best) { best = v; c = k; }   // first-max == jnp.argmax
        }
        const int lj = ((const int*)&lb)[j];
        const bool m = (best > 0.8f) & (c > 0) & ((c == lj) | (!lab));
        if (m) {
            wd |= (4u | (unsigned)(c - 1)) << (3 * j);
            atomicAdd(&lcnt[c - 1], 1.f);
        }
    }
    mask[g] = wd;
    __syncthreads();
    if (t < NC) {
        float c = lcnt[t];
        if (c != 0.f)
            atomicAdd(&part[(size_t)(blockIdx.x & (NPART - 1)) * PARTSZ + 256 + t], c);
    }
}

// K2: channel-split sweep. One block = one (batch, channel, segment):
// a single fully-sequential 110.6 KB feat run. Mask words are L2-hot.
__global__ __launch_bounds__(256) void pm_sweep(
    const float* __restrict__ feat, const unsigned int* __restrict__ mask,
    float* __restrict__ part)
{
    const int t = threadIdx.x, l = t & 63;
    const int bi = blockIdx.x;
    const int b   = bi >> 11;                    // / (CCH*NSEG) == 2048
    const int rem = bi & 2047;
    const int c   = rem >> 5;                    // channel
    const int seg = rem & 31;
    const int g0  = seg * SEGG;

    const float4* fb = (const float4*)(feat + (size_t)(b * CCH + c) * HWD);
    const unsigned int* mb = mask + (size_t)b * PLANE4;

    float s0 = 0.f, s1 = 0.f, s2 = 0.f, s3 = 0.f;
    float q0 = 0.f, q1 = 0.f, q2 = 0.f, q3 = 0.f;

    #pragma unroll 3
    for (int i = 0; i < ITER; ++i) {
        const int gg = g0 + i * 256 + t;
        const unsigned int wm = mb[gg];
        const float4 f = fb[gg];
        #pragma unroll
        for (int j = 0; j < 4; ++j) {
            const int bits = (wm >> (3 * j)) & 7;
            const float v = ((const float*)&f)[j];
            const float v2 = v * v;
            if (bits == 4) { s0 += v; q0 += v2; }
            if (bits == 5) { s1 += v; q1 += v2; }
            if (bits == 6) { s2 += v; q2 += v2; }
            if (bits == 7) { s3 += v; q3 += v2; }
        }
    }

    // full-wave butterfly: every lane ends with wave totals
    #pragma unroll
    for (int o = 1; o < 64; o <<= 1) {
        s0 += __shfl_xor(s0, o); s1 += __shfl_xor(s1, o);
        s2 += __shfl_xor(s2, o); s3 += __shfl_xor(s3, o);
        q0 += __shfl_xor(q0, o); q1 += __shfl_xor(q1, o);
        q2 += __shfl_xor(q2, o); q3 += __shfl_xor(q3, o);
    }

    float* dst = part + (size_t)(bi & (NPART - 1)) * PARTSZ;
    if (l < NC) {
        const float sv = (l == 0) ? s0 : (l == 1) ? s1 : (l == 2) ? s2 : s3;
        if (sv != 0.f) atomicAdd(&dst[l * 64 + c], sv);
    } else if (l < 2 * NC) {
        const int k = l - NC;
        const float qv = (k == 0) ? q0 : (k == 1) ? q1 : (k == 2) ? q2 : q3;
        if (qv != 0.f) atomicAdd(&dst[260 + k], qv);
    }
}

__global__ __launch_bounds__(256) void pm_pass2(
    const float* __restrict__ part, const float* __restrict__ proto,
    float* __restrict__ out)
{
    __shared__ float scnt[NC], ssq[NC], smu[NC * CCH], sred[4];
    __shared__ float s_intra;
    const int t = threadIdx.x;
    const int q = t >> 6;

    float s = 0.f;
    #pragma unroll
    for (int p = 0; p < NPART; ++p) s += part[p * PARTSZ + t];
    if (t < 2 * NC) {
        float a = 0.f;
        #pragma unroll
        for (int p = 0; p < NPART; ++p) a += part[p * PARTSZ + 256 + t];
        if (t < NC) scnt[t] = a; else ssq[t - NC] = a;
    }
    __syncthreads();

    const float cq = scnt[q];
    const float mean = s / fmaxf(cq, 1.f);
    const float pold = proto[t];                       // (4,64) row-major == t
    const float mu = (cq > 0.f) ? 0.9f * pold + 0.1f * mean : pold;
    out[3 + t] = mu;
    smu[t] = mu;

    // loss_intra numerator partial: -2*sums*mu + cnt*mu^2  (sumsq added at the end)
    float pi = -2.f * s * mu + cq * mu * mu;
    #pragma unroll
    for (int o = 1; o < 64; o <<= 1) pi += __shfl_xor(pi, o);
    if ((t & 63) == 0) sred[t >> 6] = pi;
    __syncthreads();

    if (t == 0) {
        float num = sred[0] + sred[1] + sred[2] + sred[3]
                  + ssq[0] + ssq[1] + ssq[2] + ssq[3];
        float nv = scnt[0] + scnt[1] + scnt[2] + scnt[3];
        s_intra = num / fmaxf(nv, 1.f);
    }
    __syncthreads();

    if (t < 64) {
        const int pi_[6] = {0, 0, 0, 1, 1, 2};
        const int pj_[6] = {1, 2, 3, 2, 3, 3};
        float acc = 0.f;
        #pragma unroll
        for (int e = 0; e < 6; ++e) {
            float d = smu[pi_[e] * 64 + t] - smu[pj_[e] * 64 + t];
            float d2 = d * d;
            #pragma unroll
            for (int o = 1; o < 64; o <<= 1) d2 += __shfl_xor(d2, o);
            float dist = sqrtf(d2 + 1e-12f);
            float vv = fmaxf(1.f - dist, 0.f);
            acc += vv * vv;
        }
        if (t == 0) {
            float li = acc / 6.f;                      // n_pairs = 6
            out[0] = s_intra + 0.1f * li;              // lambda_intra=1, lambda_inter=0.1
            out[1] = s_intra;
            out[2] = li;
        }
    }
}

extern "C" void kernel_launch(void* const* d_in, const int* in_sizes, int n_in,
                              void* d_out, int out_size, void* d_ws, size_t ws_size,
                              hipStream_t stream) {
    const float* feat         = (const float*)d_in[0];
    const float* pred         = (const float*)d_in[1];
    const int* label          = (const int*)d_in[2];
    const unsigned char* ilab = (const unsigned char*)d_in[3];   // jnp bool = 1 byte
    const float* proto        = (const float*)d_in[4];
    float* out                = (float*)d_out;
    float* part               = (float*)d_ws;
    unsigned int* mask        = (unsigned int*)((char*)d_ws + MASK_OFF_BYTES);

    hipLaunchKernelGGL(pm_zero,  dim3(1),     dim3(256), 0, stream, part);
    hipLaunchKernelGGL(pm_mask,  dim3(NBLKM), dim3(256), 0, stream,
                       pred, label, ilab, mask, part);
    hipLaunchKernelGGL(pm_sweep, dim3(NBLKS), dim3(256), 0, stream, feat, mask, part);
    hipLaunchKernelGGL(pm_pass2, dim3(1),     dim3(256), 0, stream, part, proto, out);
}

// Round 16
// 98.444 us; speedup vs baseline: 7.6201x; 1.0749x over previous
//
#include <hip/hip_runtime.h>

#define HWD 884736   // 96*96*96
#define KCLS 5
#define CCH 64
#define NC 4

typedef float  f32x4 __attribute__((ext_vector_type(4)));
typedef int    i32x4 __attribute__((ext_vector_type(4)));

constexpr int PLANE4 = HWD / 4;          // float4 groups per channel plane (221184)
constexpr int GRP_B  = HWD / 4;          // voxel-groups per batch item
constexpr int NBLKM  = 2 * GRP_B / 256;  // 1728 mask blocks of 256 groups

constexpr int ITER = 27;                 // groups per thread in sweep
constexpr int SEGG = 256 * ITER;         // 6912 groups per block (110.6 KB)
constexpr int NSEG = PLANE4 / SEGG;      // 32 segments per channel plane (exact)
constexpr int NBLKS = 2 * CCH * NSEG;    // 4096 sweep blocks

// d_ws layout (all partials are unique-slot, unconditionally written -> no zeroing)
constexpr size_t CNT_OFF  = 0;           // float4[NBLKM]          (27.6 KB)
constexpr size_t SWP_OFF  = 32768;       // float [NBLKS*8]        (128 KB)
constexpr size_t MASK_OFF = 163840;      // uint  [2*GRP_B]        (1.77 MB)

// K1: per-voxel mask word (4 voxels x 3 bits: valid|class2) + per-block counts
__global__ __launch_bounds__(256) void pm_mask(
    const float* __restrict__ pred, const int* __restrict__ label,
    const unsigned char* __restrict__ is_lab,
    unsigned int* __restrict__ mask, float4* __restrict__ cntP)
{
    __shared__ float lcnt[NC];
    const int t = threadIdx.x;
    if (t < NC) lcnt[t] = 0.f;
    __syncthreads();

    const int g = blockIdx.x * 256 + t;          // global float4-group id
    const int b = (blockIdx.x >= NBLKM / 2);     // block never straddles batch
    const int gg = g - b * GRP_B;

    const f32x4* pb = (const f32x4*)(pred + (size_t)b * KCLS * HWD) + gg;
    f32x4 pk[KCLS];
    #pragma unroll
    for (int k = 0; k < KCLS; ++k) pk[k] = __builtin_nontemporal_load(pb + (size_t)k * PLANE4);
    const i32x4 lb = __builtin_nontemporal_load((const i32x4*)(label + (size_t)b * HWD) + gg);
    const bool lab = is_lab[b] != 0;

    unsigned int wd = 0;
    #pragma unroll
    for (int j = 0; j < 4; ++j) {
        float best = -1.f; int c = 0;
        #pragma unroll
        for (int k = 0; k < KCLS; ++k) {
            float v = pk[k][j];
            if (v > best) { best = v; c = k; }   // first-max == jnp.argmax
        }
        const int lj = lb[j];
        const bool m = (best > 0.8f) & (c > 0) & ((c == lj) | (!lab));
        if (m) {
            wd |= (4u | (unsigned)(c - 1)) << (3 * j);
            atomicAdd(&lcnt[c - 1], 1.f);
        }
    }
    mask[g] = wd;
    __syncthreads();
    if (t == 0) cntP[blockIdx.x] = make_float4(lcnt[0], lcnt[1], lcnt[2], lcnt[3]);
}

// K2: channel-split sweep. One block = one (batch, channel, segment):
// a single fully-sequential 110.6 KB feat run (nontemporal). Mask words L2-hot.
__global__ __launch_bounds__(256) void pm_sweep(
    const float* __restrict__ feat, const unsigned int* __restrict__ mask,
    float* __restrict__ partS)
{
    __shared__ float ws8[4][8];
    const int t = threadIdx.x, w = t >> 6, l = t & 63;
    const int bi = blockIdx.x;
    const int b   = bi >> 11;                    // / (CCH*NSEG) == 2048
    const int rem = bi & 2047;
    const int c   = rem >> 5;                    // channel
    const int seg = rem & 31;
    const int g0  = seg * SEGG;

    const f32x4* fb = (const f32x4*)(feat + (size_t)(b * CCH + c) * HWD);
    const unsigned int* mb = mask + (size_t)b * PLANE4;

    float s0 = 0.f, s1 = 0.f, s2 = 0.f, s3 = 0.f;
    float q0 = 0.f, q1 = 0.f, q2 = 0.f, q3 = 0.f;

    #pragma unroll 3
    for (int i = 0; i < ITER; ++i) {
        const int gg = g0 + i * 256 + t;
        const unsigned int wm = mb[gg];
        const f32x4 f = __builtin_nontemporal_load(fb + gg);
        #pragma unroll
        for (int j = 0; j < 4; ++j) {
            const int bits = (wm >> (3 * j)) & 7;
            const float v = f[j];
            const float v2 = v * v;
            if (bits == 4) { s0 += v; q0 += v2; }
            if (bits == 5) { s1 += v; q1 += v2; }
            if (bits == 6) { s2 += v; q2 += v2; }
            if (bits == 7) { s3 += v; q3 += v2; }
        }
    }

    // wave butterfly -> all lanes hold wave totals
    #pragma unroll
    for (int o = 1; o < 64; o <<= 1) {
        s0 += __shfl_xor(s0, o); s1 += __shfl_xor(s1, o);
        s2 += __shfl_xor(s2, o); s3 += __shfl_xor(s3, o);
        q0 += __shfl_xor(q0, o); q1 += __shfl_xor(q1, o);
        q2 += __shfl_xor(q2, o); q3 += __shfl_xor(q3, o);
    }
    if (l < 8) {
        const float v = (l == 0) ? s0 : (l == 1) ? s1 : (l == 2) ? s2 : (l == 3) ? s3
                      : (l == 4) ? q0 : (l == 5) ? q1 : (l == 6) ? q2 : q3;
        ws8[w][l] = v;
    }
    __syncthreads();
    if (t < 8)   // unique-slot, unconditional: no zero-init needed anywhere
        partS[(size_t)bi * 8 + t] = ws8[0][t] + ws8[1][t] + ws8[2][t] + ws8[3][t];
}

// K3: reduce partials + EMA prototypes + losses
__global__ __launch_bounds__(256) void pm_pass2(
    const float* __restrict__ partS, const float4* __restrict__ cntP,
    const float* __restrict__ proto, float* __restrict__ out)
{
    __shared__ float scnt[NC], ssq[NC], smu[NC * CCH], sred[4];
    __shared__ float4 sc4[4];
    __shared__ float q4[4][4];
    __shared__ float s_intra;
    const int t = threadIdx.x, w = t >> 6, l = t & 63;
    const int q = t >> 6;          // class for the (k,c)=(t>>6,t&63) mapping
    const int c = t & 63;

    // ---- counts: sum 1728 float4 rows ----
    {
        float4 a = make_float4(0.f, 0.f, 0.f, 0.f);
        for (int i = t; i < NBLKM; i += 256) {
            const float4 v = cntP[i];
            a.x += v.x; a.y += v.y; a.z += v.z; a.w += v.w;
        }
        #pragma unroll
        for (int o = 1; o < 64; o <<= 1) {
            a.x += __shfl_xor(a.x, o); a.y += __shfl_xor(a.y, o);
            a.z += __shfl_xor(a.z, o); a.w += __shfl_xor(a.w, o);
        }
        if (l == 0) sc4[w] = a;
    }

    // ---- sums for (k=q, c): 64 slots ----
    float s = 0.f;
    #pragma unroll 4
    for (int b = 0; b < 2; ++b)
        for (int seg = 0; seg < 32; ++seg)
            s += partS[(size_t)((b * 2048) + (c * 32) + seg) * 8 + q];

    // ---- sumsq: group g=t>>2 handles blocks g, g+64, ...; kk=t&3 ----
    {
        const int g = t >> 2, kk = t & 3;
        float qq = 0.f;
        #pragma unroll 4
        for (int j = 0; j < 64; ++j)
            qq += partS[(size_t)(g + 64 * j) * 8 + 4 + kk];
        #pragma unroll
        for (int o = 4; o < 64; o <<= 1) qq += __shfl_xor(qq, o);
        if (l < 4) q4[w][l] = qq;    // lane l holds kk=l wave-partial
    }
    __syncthreads();
    if (t < NC) {
        const float4 c0 = sc4[0], c1 = sc4[1], c2 = sc4[2], c3 = sc4[3];
        const float cv = ((const float*)&c0)[t] + ((const float*)&c1)[t]
                       + ((const float*)&c2)[t] + ((const float*)&c3)[t];
        scnt[t] = cv;
        ssq[t] = q4[0][t] + q4[1][t] + q4[2][t] + q4[3][t];
    }
    __syncthreads();

    const float cq = scnt[q];
    const float mean = s / fmaxf(cq, 1.f);
    const float pold = proto[t];                       // (4,64) row-major == t
    const float mu = (cq > 0.f) ? 0.9f * pold + 0.1f * mean : pold;
    out[3 + t] = mu;
    smu[t] = mu;

    // loss_intra numerator partial: -2*sums*mu + cnt*mu^2  (sumsq added at the end)
    float pi = -2.f * s * mu + cq * mu * mu;
    #pragma unroll
    for (int o = 1; o < 64; o <<= 1) pi += __shfl_xor(pi, o);
    if ((t & 63) == 0) sred[t >> 6] = pi;
    __syncthreads();

    if (t == 0) {
        float num = sred[0] + sred[1] + sred[2] + sred[3]
                  + ssq[0] + ssq[1] + ssq[2] + ssq[3];
        float nv = scnt[0] + scnt[1] + scnt[2] + scnt[3];
        s_intra = num / fmaxf(nv, 1.f);
    }
    __syncthreads();

    if (t < 64) {
        const int pi_[6] = {0, 0, 0, 1, 1, 2};
        const int pj_[6] = {1, 2, 3, 2, 3, 3};
        float acc = 0.f;
        #pragma unroll
        for (int e = 0; e < 6; ++e) {
            float d = smu[pi_[e] * 64 + t] - smu[pj_[e] * 64 + t];
            float d2 = d * d;
            #pragma unroll
            for (int o = 1; o < 64; o <<= 1) d2 += __shfl_xor(d2, o);
            float dist = sqrtf(d2 + 1e-12f);
            float vv = fmaxf(1.f - dist, 0.f);
            acc += vv * vv;
        }
        if (t == 0) {
            float li = acc / 6.f;                      // n_pairs = 6
            out[0] = s_intra + 0.1f * li;              // lambda_intra=1, lambda_inter=0.1
            out[1] = s_intra;
            out[2] = li;
        }
    }
}

extern "C" void kernel_launch(void* const* d_in, const int* in_sizes, int n_in,
                              void* d_out, int out_size, void* d_ws, size_t ws_size,
                              hipStream_t stream) {
    const float* feat         = (const float*)d_in[0];
    const float* pred         = (const float*)d_in[1];
    const int* label          = (const int*)d_in[2];
    const unsigned char* ilab = (const unsigned char*)d_in[3];   // jnp bool = 1 byte
    const float* proto        = (const float*)d_in[4];
    float* out                = (float*)d_out;

    float4* cntP       = (float4*)((char*)d_ws + CNT_OFF);
    float* partS       = (float*)((char*)d_ws + SWP_OFF);
    unsigned int* mask = (unsigned int*)((char*)d_ws + MASK_OFF);

    hipLaunchKernelGGL(pm_mask,  dim3(NBLKM), dim3(256), 0, stream,
                       pred, label, ilab, mask, cntP);
    hipLaunchKernelGGL(pm_sweep, dim3(NBLKS), dim3(256), 0, stream, feat, mask, partS);
    hipLaunchKernelGGL(pm_pass2, dim3(1),     dim3(256), 0, stream,
                       partS, cntP, proto, out);
}